// Round 3
// baseline (1413.307 us; speedup 1.0000x reference)
//
#include <hip/hip_runtime.h>
#include <hip/hip_bf16.h>
#include <hip/hip_fp16.h>

// APPNP: h = MLP(x); 10x { h = 0.9 * (D^-1/2 (A+I) D^-1/2) h + 0.1 * h0 }
// fp32 in/out; GEMMs run bf16 MFMA with inline fp32->bf16 conversion.
// R4: byte-diet on the line-amplified paths (bf16 mirror of h, 4B/edge CSR).
// R5 (bucket-sort CSR build) REVERTED: few-cursor atomics serialize (~183ns/op
//   same-line chains, cross-XCD ping) -> 750us. Direct scatter is 160us.
// R6: prop_step 2-edges-per-load (lanes 0-31 edge j, 32-63 edge j+1): neutral.
// R7: GEMM pipeline fix — gemm1 was 159us at MfmaUtil 6.4% with HBM traffic
//   already minimal (202MB = X once): latency-bound, load latency serially
//   exposed each k-step. Now BK=64 + register prefetch: issue next tile's
//   global loads BEFORE computing current tile from LDS; reg->LDS write after
//   the compute barrier. LDS row stride 72 elems (144B: dr=8 bank alias only).

typedef __bf16 bf16x8 __attribute__((ext_vector_type(8)));
typedef float f32x4 __attribute__((ext_vector_type(4)));

static constexpr int IN = 512, HID = 256, OUT = 64;
static constexpr int LDT = 72;  // LDS row stride in bf16 elems (BK=64 + 8 pad)

static __device__ __forceinline__ ushort f2bf(float f) {
  __hip_bfloat16 b = __float2bfloat16(f);
  return *reinterpret_cast<ushort*>(&b);
}
static __device__ __forceinline__ float bf2f(ushort u) {
  unsigned int x = ((unsigned int)u) << 16;
  return __uint_as_float(x);
}
// decode low-15-bit fp16 (sign=0) weight
static __device__ __forceinline__ float h15f(unsigned int u) {
  ushort hb = (ushort)(u & 0x7FFFu);
  __half h = *reinterpret_cast<__half*>(&hb);
  return __half2float(h);
}

// ---------------- transpose fp32 [K][C] -> bf16 [C][K] ----------------
__global__ void transpose_f32_bf16(const float* __restrict__ in, ushort* __restrict__ out,
                                   int K, int C) {
  int idx = blockIdx.x * 256 + threadIdx.x;
  if (idx < K * C) {
    int n = idx / K, k = idx % K;
    out[idx] = f2bf(in[k * C + n]);
  }
}

// ---------------- GEMM1: h1 = relu(X @ W1 + b1) ----------------
// X [M,512] fp32 (cvt->bf16 inline), W1T [256,512] bf16, h1 [M,256] bf16.
// Tile 128x128, BK=64, register-prefetch pipeline (see R7 note).
__global__ __launch_bounds__(256) void gemm1(const float* __restrict__ X,
                                             const ushort* __restrict__ W1T,
                                             const float* __restrict__ b1,
                                             ushort* __restrict__ h1, int M) {
  __shared__ __align__(16) ushort As[128 * LDT];
  __shared__ __align__(16) ushort Bs[128 * LDT];
  const int tid = threadIdx.x;
  const int m0 = blockIdx.x * 128;
  const int n0 = blockIdx.y * 128;
  const int lane = tid & 63, w = tid >> 6;
  const int wr = w >> 1, wc = w & 1;
  const int lm = lane & 15, lq = lane >> 4;
  // A staging: 16 col-threads (cA*4 floats = 64 cols) x 16 rows, 8 row-groups
  const int cA = tid & 15, rA = tid >> 4;
  // B staging: 8 col-threads (cB*8 bf16 = 64 cols) x 32 rows, 4 row-groups
  const int cB = tid & 7, rB = tid >> 3;

  float4 pa[8];
  int4 pb[4];

  auto LOADA = [&](int k0) {
#pragma unroll
    for (int rr = 0; rr < 8; ++rr) {
      int gm = m0 + rA + rr * 16; gm = gm < M ? gm : M - 1;
      pa[rr] = *reinterpret_cast<const float4*>(&X[(size_t)gm * IN + k0 + cA * 4]);
    }
  };
  auto LOADB = [&](int k0) {
#pragma unroll
    for (int rr = 0; rr < 4; ++rr) {
      int n = rB + rr * 32;
      pb[rr] = *reinterpret_cast<const int4*>(&W1T[(size_t)(n0 + n) * IN + k0 + cB * 8]);
    }
  };
  auto STORE = [&]() {
#pragma unroll
    for (int rr = 0; rr < 8; ++rr) {
      ushort4 cv;
      cv.x = f2bf(pa[rr].x); cv.y = f2bf(pa[rr].y);
      cv.z = f2bf(pa[rr].z); cv.w = f2bf(pa[rr].w);
      *reinterpret_cast<ushort4*>(&As[(rA + rr * 16) * LDT + cA * 4]) = cv;
    }
#pragma unroll
    for (int rr = 0; rr < 4; ++rr)
      *reinterpret_cast<int4*>(&Bs[(rB + rr * 32) * LDT + cB * 8]) = pb[rr];
  };

  f32x4 acc[4][4] = {};

  LOADA(0); LOADB(0);
  STORE();
  __syncthreads();

  for (int k0 = 64; k0 <= IN; k0 += 64) {
    const bool more = (k0 < IN);
    if (more) { LOADA(k0); LOADB(k0); }  // in-flight during compute
#pragma unroll
    for (int kk = 0; kk < 2; ++kk) {
      bf16x8 af[4], bq[4];
#pragma unroll
      for (int mi = 0; mi < 4; ++mi)
        af[mi] = *reinterpret_cast<const bf16x8*>(
            &As[(wr * 64 + mi * 16 + lm) * LDT + kk * 32 + lq * 8]);
#pragma unroll
      for (int ni = 0; ni < 4; ++ni)
        bq[ni] = *reinterpret_cast<const bf16x8*>(
            &Bs[(wc * 64 + ni * 16 + lm) * LDT + kk * 32 + lq * 8]);
#pragma unroll
      for (int mi = 0; mi < 4; ++mi)
#pragma unroll
        for (int ni = 0; ni < 4; ++ni)
          acc[mi][ni] = __builtin_amdgcn_mfma_f32_16x16x32_bf16(af[mi], bq[ni], acc[mi][ni], 0, 0, 0);
    }
    __syncthreads();
    if (more) {
      STORE();
      __syncthreads();
    }
  }

#pragma unroll
  for (int ni = 0; ni < 4; ++ni) {
    int col = n0 + wc * 64 + ni * 16 + lm;
    float bias = b1[col];
#pragma unroll
    for (int mi = 0; mi < 4; ++mi) {
#pragma unroll
      for (int rg = 0; rg < 4; ++rg) {
        int row = m0 + wr * 64 + mi * 16 + lq * 4 + rg;
        if (row < M) {
          float v = acc[mi][ni][rg] + bias;
          v = v > 0.f ? v : 0.f;
          h1[(size_t)row * HID + col] = f2bf(v);
        }
      }
    }
  }
}

// ---------------- GEMM2: H0 = h1 @ W2 + b2, fp32 + bf16 mirror out ----------------
// h1 [M,256] bf16, W2T [64,256] bf16. Tile 128x64, BK=64, same pipeline.
__global__ __launch_bounds__(256) void gemm2(const ushort* __restrict__ h1,
                                             const ushort* __restrict__ W2T,
                                             const float* __restrict__ b2,
                                             float* __restrict__ H0f,
                                             ushort* __restrict__ H0b, int M) {
  __shared__ __align__(16) ushort As[128 * LDT];
  __shared__ __align__(16) ushort Bs[64 * LDT];
  const int tid = threadIdx.x;
  const int m0 = blockIdx.x * 128;
  const int lane = tid & 63, w = tid >> 6;
  const int lm = lane & 15, lq = lane >> 4;
  // A staging: 8 col-threads (cA*8 bf16 = 64 cols) x 32 rows, 4 row-groups
  // B staging: same cols x 32 rows, 2 row-groups
  const int cA = tid & 7, rA = tid >> 3;

  int4 pa[4];
  int4 pb[2];

  auto LOADA = [&](int k0) {
#pragma unroll
    for (int rr = 0; rr < 4; ++rr) {
      int gm = m0 + rA + rr * 32; gm = gm < M ? gm : M - 1;
      pa[rr] = *reinterpret_cast<const int4*>(&h1[(size_t)gm * HID + k0 + cA * 8]);
    }
  };
  auto LOADB = [&](int k0) {
#pragma unroll
    for (int rr = 0; rr < 2; ++rr)
      pb[rr] = *reinterpret_cast<const int4*>(&W2T[(size_t)(rA + rr * 32) * HID + k0 + cA * 8]);
  };
  auto STORE = [&]() {
#pragma unroll
    for (int rr = 0; rr < 4; ++rr)
      *reinterpret_cast<int4*>(&As[(rA + rr * 32) * LDT + cA * 8]) = pa[rr];
#pragma unroll
    for (int rr = 0; rr < 2; ++rr)
      *reinterpret_cast<int4*>(&Bs[(rA + rr * 32) * LDT + cA * 8]) = pb[rr];
  };

  f32x4 acc[2][4] = {};

  LOADA(0); LOADB(0);
  STORE();
  __syncthreads();

  for (int k0 = 64; k0 <= HID; k0 += 64) {
    const bool more = (k0 < HID);
    if (more) { LOADA(k0); LOADB(k0); }
#pragma unroll
    for (int kk = 0; kk < 2; ++kk) {
      bf16x8 af[2], bq[4];
#pragma unroll
      for (int mi = 0; mi < 2; ++mi)
        af[mi] = *reinterpret_cast<const bf16x8*>(
            &As[(w * 32 + mi * 16 + lm) * LDT + kk * 32 + lq * 8]);
#pragma unroll
      for (int ni = 0; ni < 4; ++ni)
        bq[ni] = *reinterpret_cast<const bf16x8*>(
            &Bs[(ni * 16 + lm) * LDT + kk * 32 + lq * 8]);
#pragma unroll
      for (int mi = 0; mi < 2; ++mi)
#pragma unroll
        for (int ni = 0; ni < 4; ++ni)
          acc[mi][ni] = __builtin_amdgcn_mfma_f32_16x16x32_bf16(af[mi], bq[ni], acc[mi][ni], 0, 0, 0);
    }
    __syncthreads();
    if (more) {
      STORE();
      __syncthreads();
    }
  }

#pragma unroll
  for (int ni = 0; ni < 4; ++ni) {
    int col = ni * 16 + lm;
    float bias = b2[col];
#pragma unroll
    for (int mi = 0; mi < 2; ++mi) {
#pragma unroll
      for (int rg = 0; rg < 4; ++rg) {
        int row = m0 + w * 32 + mi * 16 + lq * 4 + rg;
        if (row < M) {
          float v = acc[mi][ni][rg] + bias;
          H0f[(size_t)row * OUT + col] = v;
          H0b[(size_t)row * OUT + col] = f2bf(v);
        }
      }
    }
  }
}

// ---------------- degree / dinv / scan / CSR ----------------
__global__ void count_deg(const int* __restrict__ ei, int* __restrict__ cnt, int E) {
  int e = blockIdx.x * 256 + threadIdx.x;
  if (e < E) atomicAdd(&cnt[ei[E + e]], 1);
}

__global__ void calc_dinv(const int* __restrict__ cnt, float* __restrict__ dinv, int n) {
  int v = blockIdx.x * 256 + threadIdx.x;
  if (v < n) dinv[v] = rsqrtf((float)cnt[v] + 1.0f);  // +1: self-loop
}

// single-block exclusive scan of cnt[n] -> offs[n+1], cursor[n]; 4 elems/thread/iter
__global__ __launch_bounds__(1024) void scan_kernel(const int* __restrict__ cnt,
                                                    int* __restrict__ offs,
                                                    int* __restrict__ cursor, int n) {
  __shared__ int wsum[16];
  __shared__ int woff[16];
  __shared__ int carry_s;
  const int tid = threadIdx.x;
  const int lane = tid & 63, wid = tid >> 6;
  if (tid == 0) carry_s = 0;
  __syncthreads();
  for (int base = 0; base < n; base += 4096) {
    int i0 = base + tid * 4;
    int x[4];
#pragma unroll
    for (int j = 0; j < 4; ++j) x[j] = (i0 + j < n) ? cnt[i0 + j] : 0;
    int tsum = x[0] + x[1] + x[2] + x[3];
    int val = tsum;
#pragma unroll
    for (int d = 1; d < 64; d <<= 1) {
      int t = __shfl_up(val, d, 64);
      if (lane >= d) val += t;
    }
    if (lane == 63) wsum[wid] = val;
    __syncthreads();
    if (wid == 0) {
      int s = (lane < 16) ? wsum[lane] : 0;
      int sv = s;
#pragma unroll
      for (int d = 1; d < 16; d <<= 1) {
        int t = __shfl_up(sv, d, 64);
        if (lane >= d) sv += t;
      }
      if (lane < 16) woff[lane] = sv - s;
    }
    __syncthreads();
    int excl = carry_s + woff[wid] + (val - tsum);
#pragma unroll
    for (int j = 0; j < 4; ++j) {
      if (i0 + j < n) { offs[i0 + j] = excl; cursor[i0 + j] = excl; }
      excl += x[j];
    }
    __syncthreads();
    if (tid == 1023) carry_s = excl;
    __syncthreads();
  }
  if (tid == 0) offs[n] = carry_s;
}

// pack (src<<15) | fp16bits(w): src < 2^17, w > 0 so fp16 sign bit is dropped
__global__ void fill_csr(const int* __restrict__ ei, int* __restrict__ cursor,
                         const float* __restrict__ dinv, unsigned int* __restrict__ csr,
                         int E) {
  int e = blockIdx.x * 256 + threadIdx.x;
  if (e < E) {
    int s = ei[e], d = ei[E + e];
    int p = atomicAdd(&cursor[d], 1);
    float w = dinv[s] * dinv[d];
    __half hw = __float2half(w);
    unsigned int hb = *reinterpret_cast<ushort*>(&hw);
    csr[p] = (((unsigned int)s) << 15) | hb;
  }
}

// ---------------- propagation: one wave per node ----------------
// Lane l batch-fetches csr[base+l] (256B coalesced per 64 edges), shfl-broadcasts.
// 2 edges per load: lanes 0-31 read edge (j+2k) row as uint (features 2c,2c+1),
// lanes 32-63 read edge (j+2k+1). 16 loads in flight = 32 edges. Even/odd-edge
// partial sums combined with shfl_xor(32); fp32 write by lanes<32, bf16 by lanes>=32.
template <bool WRITE_BF>
__global__ __launch_bounds__(256) void prop_step(const float* __restrict__ hinf,
                                                 const ushort* __restrict__ hinb,
                                                 float* __restrict__ houtf,
                                                 ushort* __restrict__ houtb,
                                                 const float* __restrict__ h0,
                                                 const int* __restrict__ offs,
                                                 const unsigned int* __restrict__ csr,
                                                 const float* __restrict__ dinv, int n) {
  int gw = (blockIdx.x * 256 + threadIdx.x) >> 6;
  int lane = threadIdx.x & 63;
  if (gw >= n) return;
  const unsigned int* hin32 = (const unsigned int*)hinb;
  const int c = lane & 31;       // feature pair index (features 2c, 2c+1)
  const int half = lane >> 5;    // 0: even-slot edges, 1: odd-slot edges
  float alo[8], ahi[8];
#pragma unroll
  for (int k = 0; k < 8; ++k) { alo[k] = 0.f; ahi[k] = 0.f; }
  int e0 = offs[gw], e1 = offs[gw + 1];
  for (int base = e0; base < e1; base += 64) {
    int rem = e1 - base;
    // padded lanes: u=0 -> src=0, w=+0 (row 0 is valid; contribution is 0)
    unsigned int my = (lane < rem) ? csr[base + lane] : 0u;
    int cnt = rem < 64 ? rem : 64;
    int cnt32 = (cnt + 31) & ~31;
    for (int j = 0; j < cnt32; j += 32) {
      unsigned int u[16];
#pragma unroll
      for (int k = 0; k < 16; ++k)
        u[k] = (unsigned int)__shfl((int)my, j + 2 * k + half);
      unsigned int v[16];
#pragma unroll
      for (int k = 0; k < 16; ++k)
        v[k] = hin32[(size_t)(u[k] >> 15) * 32 + c];
#pragma unroll
      for (int k = 0; k < 16; ++k) {
        float w = h15f(u[k]);
        float f0 = __uint_as_float(v[k] << 16);
        float f1 = __uint_as_float(v[k] & 0xFFFF0000u);
        alo[k & 7] = fmaf(w, f0, alo[k & 7]);
        ahi[k & 7] = fmaf(w, f1, ahi[k & 7]);
      }
    }
  }
  float a0 = ((alo[0] + alo[1]) + (alo[2] + alo[3])) + ((alo[4] + alo[5]) + (alo[6] + alo[7]));
  float a1 = ((ahi[0] + ahi[1]) + (ahi[2] + ahi[3])) + ((ahi[4] + ahi[5]) + (ahi[6] + ahi[7]));
  // combine even/odd-edge halves (partner lane holds same features, other parity)
  a0 += __shfl_xor(a0, 32, 64);
  a1 += __shfl_xor(a1, 32, 64);
  float dv = dinv[gw];
  float2 hf = ((const float2*)hinf)[(size_t)gw * 32 + c];
  float2 h0f = ((const float2*)h0)[(size_t)gw * 32 + c];
  float o0 = 0.9f * (a0 + dv * dv * hf.x) + 0.1f * h0f.x;
  float o1 = 0.9f * (a1 + dv * dv * hf.y) + 0.1f * h0f.y;
  if (half == 0) {
    float2 ov; ov.x = o0; ov.y = o1;
    ((float2*)houtf)[(size_t)gw * 32 + c] = ov;
  } else if (WRITE_BF) {
    unsigned int pk = (unsigned int)f2bf(o0) | ((unsigned int)f2bf(o1) << 16);
    ((unsigned int*)houtb)[(size_t)gw * 32 + c] = pk;
  }
}

extern "C" void kernel_launch(void* const* d_in, const int* in_sizes, int n_in,
                              void* d_out, int out_size, void* d_ws, size_t ws_size,
                              hipStream_t stream) {
  const float* X  = (const float*)d_in[0];  // [N,512] f32
  const int*   EI = (const int*)d_in[1];    // [2,E] int32
  const float* W1 = (const float*)d_in[2];  // [512,256] f32
  const float* b1 = (const float*)d_in[3];  // [256] f32
  const float* W2 = (const float*)d_in[4];  // [256,64] f32
  const float* b2 = (const float*)d_in[5];  // [64] f32
  float* out = (float*)d_out;               // [N,64] f32

  const int N = in_sizes[0] / IN;  // 100000
  const int E = in_sizes[1] / 2;   // 3200000

  char* ws = (char*)d_ws;
  size_t o = 0;
  auto alloc = [&](size_t b) {
    char* p = ws + o;
    o = (o + b + 255) & ~(size_t)255;
    return p;
  };
  float*  H0f  = (float*)alloc((size_t)N * OUT * 4);
  ushort* H0b  = (ushort*)alloc((size_t)N * OUT * 2);
  float*  hAf  = (float*)alloc((size_t)N * OUT * 4);
  ushort* hAb  = (ushort*)alloc((size_t)N * OUT * 2);
  float*  hBf  = (float*)alloc((size_t)N * OUT * 4);
  ushort* hBb  = (ushort*)alloc((size_t)N * OUT * 2);
  ushort* h1   = (ushort*)alloc((size_t)N * HID * 2);
  ushort* W1T  = (ushort*)alloc((size_t)IN * HID * 2);
  ushort* W2T  = (ushort*)alloc((size_t)HID * OUT * 2);
  int*    cnt  = (int*)alloc((size_t)N * 4);
  int*    offs = (int*)alloc((size_t)(N + 1) * 4);
  int*    curs = (int*)alloc((size_t)N * 4);
  float*  dinv = (float*)alloc((size_t)N * 4);
  unsigned int* csr = (unsigned int*)alloc((size_t)E * 4);
  (void)ws_size; (void)n_in; (void)out_size;

  transpose_f32_bf16<<<(IN * HID + 255) / 256, 256, 0, stream>>>(W1, W1T, IN, HID);
  transpose_f32_bf16<<<(HID * OUT + 255) / 256, 256, 0, stream>>>(W2, W2T, HID, OUT);

  gemm1<<<dim3((N + 127) / 128, HID / 128), 256, 0, stream>>>(X, W1T, b1, h1, N);
  gemm2<<<(N + 127) / 128, 256, 0, stream>>>(h1, W2T, b2, H0f, H0b, N);

  hipMemsetAsync(cnt, 0, (size_t)N * 4, stream);
  count_deg<<<(E + 255) / 256, 256, 0, stream>>>(EI, cnt, E);
  calc_dinv<<<(N + 255) / 256, 256, 0, stream>>>(cnt, dinv, N);
  scan_kernel<<<1, 1024, 0, stream>>>(cnt, offs, curs, N);
  fill_csr<<<(E + 255) / 256, 256, 0, stream>>>(EI, curs, dinv, csr, E);

  const int pgrid = (N * OUT + 255) / 256;  // one wave per node
  prop_step<true><<<pgrid, 256, 0, stream>>>(H0f, H0b, hAf, hAb, H0f, offs, csr, dinv, N);
  for (int i = 0; i < 4; ++i) {
    prop_step<true><<<pgrid, 256, 0, stream>>>(hAf, hAb, hBf, hBb, H0f, offs, csr, dinv, N);
    prop_step<true><<<pgrid, 256, 0, stream>>>(hBf, hBb, hAf, hAb, H0f, offs, csr, dinv, N);
  }
  prop_step<false><<<pgrid, 256, 0, stream>>>(hAf, hAb, out, nullptr, H0f, offs, csr, dinv, N);
}

// Round 4
// 1407.882 us; speedup vs baseline: 1.0039x; 1.0039x over previous
//
#include <hip/hip_runtime.h>
#include <hip/hip_bf16.h>
#include <hip/hip_fp16.h>

// APPNP: h = MLP(x); 10x { h = 0.9 * (D^-1/2 (A+I) D^-1/2) h + 0.1 * h0 }
// fp32 in/out; GEMMs run bf16 MFMA with inline fp32->bf16 conversion.
// R4: byte-diet on the line-amplified paths (bf16 mirror of h, 4B/edge CSR).
// R5 (bucket-sort CSR build) REVERTED: few-cursor atomics serialize (~183ns/op
//   same-line chains, cross-XCD ping) -> 750us. Keep per-node cursors.
// R6: prop_step 2-edges-per-load (lanes 0-31 edge j, 32-63 edge j+1): neutral.
// R7 (GEMM reg-prefetch) REVERTED: pa/pb live across barriers -> VGPR 100,
//   LDS 37KB, occupancy 19%, WRITE_SIZE 78->207MB (spill/eviction), 175us.
//   Simple 2-barrier BK=32 loop restored (159us).
// R8: fill_csr dst-range partitioning — 197MB partial-line write drains came
//   from 4B scatters into 12.8MB assembled cross-XCD over the whole kernel.
//   Now grid = 8 ranges x 196 chunks; block (bid&7) filters its 16K-edge chunk
//   to a 12.5K-node dst range: csr window ~1.6MB + cursor slice ~50KB per
//   range class -> L2-resident (bid%8~XCD heuristic; correctness-independent),
//   lines assemble fully. EI re-read x8 is L3-absorbed. Atomics stay spread
//   over 100K cursors (32/addr — no R5 serialization).

typedef __bf16 bf16x8 __attribute__((ext_vector_type(8)));
typedef float f32x4 __attribute__((ext_vector_type(4)));

static constexpr int IN = 512, HID = 256, OUT = 64;
static constexpr int LDT = 40;   // LDS row stride in bf16 elems
static constexpr int CSR_CH = 16384;  // edges per fill_csr chunk

static __device__ __forceinline__ ushort f2bf(float f) {
  __hip_bfloat16 b = __float2bfloat16(f);
  return *reinterpret_cast<ushort*>(&b);
}
static __device__ __forceinline__ float bf2f(ushort u) {
  unsigned int x = ((unsigned int)u) << 16;
  return __uint_as_float(x);
}
// decode low-15-bit fp16 (sign=0) weight
static __device__ __forceinline__ float h15f(unsigned int u) {
  ushort hb = (ushort)(u & 0x7FFFu);
  __half h = *reinterpret_cast<__half*>(&hb);
  return __half2float(h);
}

// ---------------- transpose fp32 [K][C] -> bf16 [C][K] ----------------
__global__ void transpose_f32_bf16(const float* __restrict__ in, ushort* __restrict__ out,
                                   int K, int C) {
  int idx = blockIdx.x * 256 + threadIdx.x;
  if (idx < K * C) {
    int n = idx / K, k = idx % K;
    out[idx] = f2bf(in[k * C + n]);
  }
}

// ---------------- GEMM1: h1 = relu(X @ W1 + b1) ----------------
// X [M,512] fp32 (cvt->bf16 inline), W1T [256,512] bf16, h1 [M,256] bf16. Tile 128x128x32.
__global__ __launch_bounds__(256) void gemm1(const float* __restrict__ X,
                                             const ushort* __restrict__ W1T,
                                             const float* __restrict__ b1,
                                             ushort* __restrict__ h1, int M) {
  __shared__ __align__(16) ushort As[128 * LDT];
  __shared__ __align__(16) ushort Bs[128 * LDT];
  const int tid = threadIdx.x;
  const int m0 = blockIdx.x * 128;
  const int n0 = blockIdx.y * 128;
  const int lane = tid & 63, w = tid >> 6;
  const int wr = w >> 1, wc = w & 1;
  const int lm = lane & 15, lq = lane >> 4;
  const int cB = tid & 3, rB = tid >> 2;   // B staging: 16B bf16 chunks
  const int cA = tid & 7, rA = tid >> 3;   // A staging: float4 -> 4 bf16 (8B)

  f32x4 acc[4][4] = {};

  for (int k0 = 0; k0 < IN; k0 += 32) {
#pragma unroll
    for (int rr = 0; rr < 4; ++rr) {
      int m = rA + rr * 32;
      int gm = m0 + m; gm = gm < M ? gm : M - 1;
      float4 f = *reinterpret_cast<const float4*>(&X[(size_t)gm * IN + k0 + cA * 4]);
      ushort4 cv;
      cv.x = f2bf(f.x); cv.y = f2bf(f.y); cv.z = f2bf(f.z); cv.w = f2bf(f.w);
      *reinterpret_cast<ushort4*>(&As[m * LDT + cA * 4]) = cv;
    }
#pragma unroll
    for (int rr = 0; rr < 2; ++rr) {
      int n = rB + rr * 64;
      *reinterpret_cast<int4*>(&Bs[n * LDT + cB * 8]) =
          *reinterpret_cast<const int4*>(&W1T[(size_t)(n0 + n) * IN + k0 + cB * 8]);
    }
    __syncthreads();
    bf16x8 af[4], bq[4];
#pragma unroll
    for (int mi = 0; mi < 4; ++mi)
      af[mi] = *reinterpret_cast<const bf16x8*>(&As[(wr * 64 + mi * 16 + lm) * LDT + lq * 8]);
#pragma unroll
    for (int ni = 0; ni < 4; ++ni)
      bq[ni] = *reinterpret_cast<const bf16x8*>(&Bs[(wc * 64 + ni * 16 + lm) * LDT + lq * 8]);
#pragma unroll
    for (int mi = 0; mi < 4; ++mi)
#pragma unroll
      for (int ni = 0; ni < 4; ++ni)
        acc[mi][ni] = __builtin_amdgcn_mfma_f32_16x16x32_bf16(af[mi], bq[ni], acc[mi][ni], 0, 0, 0);
    __syncthreads();
  }

#pragma unroll
  for (int ni = 0; ni < 4; ++ni) {
    int col = n0 + wc * 64 + ni * 16 + lm;
    float bias = b1[col];
#pragma unroll
    for (int mi = 0; mi < 4; ++mi) {
#pragma unroll
      for (int rg = 0; rg < 4; ++rg) {
        int row = m0 + wr * 64 + mi * 16 + lq * 4 + rg;
        if (row < M) {
          float v = acc[mi][ni][rg] + bias;
          v = v > 0.f ? v : 0.f;
          h1[(size_t)row * HID + col] = f2bf(v);
        }
      }
    }
  }
}

// ---------------- GEMM2: H0 = h1 @ W2 + b2, fp32 + bf16 mirror out ----------------
__global__ __launch_bounds__(256) void gemm2(const ushort* __restrict__ h1,
                                             const ushort* __restrict__ W2T,
                                             const float* __restrict__ b2,
                                             float* __restrict__ H0f,
                                             ushort* __restrict__ H0b, int M) {
  __shared__ __align__(16) ushort As[128 * LDT];
  __shared__ __align__(16) ushort Bs[64 * LDT];
  const int tid = threadIdx.x;
  const int m0 = blockIdx.x * 128;
  const int lane = tid & 63, w = tid >> 6;
  const int lm = lane & 15, lq = lane >> 4;
  const int c = tid & 3, r = tid >> 2;

  f32x4 acc[2][4] = {};

  for (int k0 = 0; k0 < HID; k0 += 32) {
#pragma unroll
    for (int rr = 0; rr < 2; ++rr) {
      int m = r + rr * 64;
      int gm = m0 + m; gm = gm < M ? gm : M - 1;
      *reinterpret_cast<int4*>(&As[m * LDT + c * 8]) =
          *reinterpret_cast<const int4*>(&h1[(size_t)gm * HID + k0 + c * 8]);
    }
    *reinterpret_cast<int4*>(&Bs[r * LDT + c * 8]) =
        *reinterpret_cast<const int4*>(&W2T[(size_t)r * HID + k0 + c * 8]);
    __syncthreads();
    bf16x8 af[2], bq[4];
#pragma unroll
    for (int mi = 0; mi < 2; ++mi)
      af[mi] = *reinterpret_cast<const bf16x8*>(&As[(w * 32 + mi * 16 + lm) * LDT + lq * 8]);
#pragma unroll
    for (int ni = 0; ni < 4; ++ni)
      bq[ni] = *reinterpret_cast<const bf16x8*>(&Bs[(ni * 16 + lm) * LDT + lq * 8]);
#pragma unroll
    for (int mi = 0; mi < 2; ++mi)
#pragma unroll
      for (int ni = 0; ni < 4; ++ni)
        acc[mi][ni] = __builtin_amdgcn_mfma_f32_16x16x32_bf16(af[mi], bq[ni], acc[mi][ni], 0, 0, 0);
    __syncthreads();
  }

#pragma unroll
  for (int ni = 0; ni < 4; ++ni) {
    int col = ni * 16 + lm;
    float bias = b2[col];
#pragma unroll
    for (int mi = 0; mi < 2; ++mi) {
#pragma unroll
      for (int rg = 0; rg < 4; ++rg) {
        int row = m0 + w * 32 + mi * 16 + lq * 4 + rg;
        if (row < M) {
          float v = acc[mi][ni][rg] + bias;
          H0f[(size_t)row * OUT + col] = v;
          H0b[(size_t)row * OUT + col] = f2bf(v);
        }
      }
    }
  }
}

// ---------------- degree / dinv / scan / CSR ----------------
__global__ void count_deg(const int* __restrict__ ei, int* __restrict__ cnt, int E) {
  int e = blockIdx.x * 256 + threadIdx.x;
  if (e < E) atomicAdd(&cnt[ei[E + e]], 1);
}

__global__ void calc_dinv(const int* __restrict__ cnt, float* __restrict__ dinv, int n) {
  int v = blockIdx.x * 256 + threadIdx.x;
  if (v < n) dinv[v] = rsqrtf((float)cnt[v] + 1.0f);  // +1: self-loop
}

// single-block exclusive scan of cnt[n] -> offs[n+1], cursor[n]; 4 elems/thread/iter
__global__ __launch_bounds__(1024) void scan_kernel(const int* __restrict__ cnt,
                                                    int* __restrict__ offs,
                                                    int* __restrict__ cursor, int n) {
  __shared__ int wsum[16];
  __shared__ int woff[16];
  __shared__ int carry_s;
  const int tid = threadIdx.x;
  const int lane = tid & 63, wid = tid >> 6;
  if (tid == 0) carry_s = 0;
  __syncthreads();
  for (int base = 0; base < n; base += 4096) {
    int i0 = base + tid * 4;
    int x[4];
#pragma unroll
    for (int j = 0; j < 4; ++j) x[j] = (i0 + j < n) ? cnt[i0 + j] : 0;
    int tsum = x[0] + x[1] + x[2] + x[3];
    int val = tsum;
#pragma unroll
    for (int d = 1; d < 64; d <<= 1) {
      int t = __shfl_up(val, d, 64);
      if (lane >= d) val += t;
    }
    if (lane == 63) wsum[wid] = val;
    __syncthreads();
    if (wid == 0) {
      int s = (lane < 16) ? wsum[lane] : 0;
      int sv = s;
#pragma unroll
      for (int d = 1; d < 16; d <<= 1) {
        int t = __shfl_up(sv, d, 64);
        if (lane >= d) sv += t;
      }
      if (lane < 16) woff[lane] = sv - s;
    }
    __syncthreads();
    int excl = carry_s + woff[wid] + (val - tsum);
#pragma unroll
    for (int j = 0; j < 4; ++j) {
      if (i0 + j < n) { offs[i0 + j] = excl; cursor[i0 + j] = excl; }
      excl += x[j];
    }
    __syncthreads();
    if (tid == 1023) carry_s = excl;
    __syncthreads();
  }
  if (tid == 0) offs[n] = carry_s;
}

// pack (src<<15) | fp16bits(w): src < 2^17, w > 0 so fp16 sign bit is dropped.
// R8: dst-range partitioned. bid&7 selects a ~12.5K-node dst range (bid%8~XCD
// round-robin heuristic); bid>>3 selects a 16K-edge chunk. Each range class
// writes only its ~1.6MB csr window + 50KB cursor slice -> lines assemble in
// L2 instead of draining partial. EI re-reads (x8) are L3-absorbed.
__global__ __launch_bounds__(256) void fill_csr(const int* __restrict__ ei,
                                                int* __restrict__ cursor,
                                                const float* __restrict__ dinv,
                                                unsigned int* __restrict__ csr,
                                                int E, int n) {
  const int r = blockIdx.x & 7;
  const int chunk = blockIdx.x >> 3;
  const int RN = (n + 7) >> 3;
  const int lo = r * RN;
  const int hi = (lo + RN < n) ? lo + RN : n;
  int e0 = chunk * CSR_CH;
  int e1 = e0 + CSR_CH; if (e1 > E) e1 = E;
  for (int e = e0 + threadIdx.x; e < e1; e += 256) {
    int d = ei[E + e];
    if (d >= lo && d < hi) {
      int s = ei[e];
      int p = atomicAdd(&cursor[d], 1);
      float w = dinv[s] * dinv[d];
      __half hw = __float2half(w);
      unsigned int hb = *reinterpret_cast<ushort*>(&hw);
      csr[p] = (((unsigned int)s) << 15) | hb;
    }
  }
}

// ---------------- propagation: one wave per node ----------------
// Lane l batch-fetches csr[base+l] (256B coalesced per 64 edges), shfl-broadcasts.
// 2 edges per load: lanes 0-31 read edge (j+2k) row as uint (features 2c,2c+1),
// lanes 32-63 read edge (j+2k+1). 16 loads in flight = 32 edges. Even/odd-edge
// partial sums combined with shfl_xor(32); fp32 write by lanes<32, bf16 by lanes>=32.
template <bool WRITE_BF>
__global__ __launch_bounds__(256) void prop_step(const float* __restrict__ hinf,
                                                 const ushort* __restrict__ hinb,
                                                 float* __restrict__ houtf,
                                                 ushort* __restrict__ houtb,
                                                 const float* __restrict__ h0,
                                                 const int* __restrict__ offs,
                                                 const unsigned int* __restrict__ csr,
                                                 const float* __restrict__ dinv, int n) {
  int gw = (blockIdx.x * 256 + threadIdx.x) >> 6;
  int lane = threadIdx.x & 63;
  if (gw >= n) return;
  const unsigned int* hin32 = (const unsigned int*)hinb;
  const int c = lane & 31;       // feature pair index (features 2c, 2c+1)
  const int half = lane >> 5;    // 0: even-slot edges, 1: odd-slot edges
  float alo[8], ahi[8];
#pragma unroll
  for (int k = 0; k < 8; ++k) { alo[k] = 0.f; ahi[k] = 0.f; }
  int e0 = offs[gw], e1 = offs[gw + 1];
  for (int base = e0; base < e1; base += 64) {
    int rem = e1 - base;
    // padded lanes: u=0 -> src=0, w=+0 (row 0 is valid; contribution is 0)
    unsigned int my = (lane < rem) ? csr[base + lane] : 0u;
    int cnt = rem < 64 ? rem : 64;
    int cnt32 = (cnt + 31) & ~31;
    for (int j = 0; j < cnt32; j += 32) {
      unsigned int u[16];
#pragma unroll
      for (int k = 0; k < 16; ++k)
        u[k] = (unsigned int)__shfl((int)my, j + 2 * k + half);
      unsigned int v[16];
#pragma unroll
      for (int k = 0; k < 16; ++k)
        v[k] = hin32[(size_t)(u[k] >> 15) * 32 + c];
#pragma unroll
      for (int k = 0; k < 16; ++k) {
        float w = h15f(u[k]);
        float f0 = __uint_as_float(v[k] << 16);
        float f1 = __uint_as_float(v[k] & 0xFFFF0000u);
        alo[k & 7] = fmaf(w, f0, alo[k & 7]);
        ahi[k & 7] = fmaf(w, f1, ahi[k & 7]);
      }
    }
  }
  float a0 = ((alo[0] + alo[1]) + (alo[2] + alo[3])) + ((alo[4] + alo[5]) + (alo[6] + alo[7]));
  float a1 = ((ahi[0] + ahi[1]) + (ahi[2] + ahi[3])) + ((ahi[4] + ahi[5]) + (ahi[6] + ahi[7]));
  // combine even/odd-edge halves (partner lane holds same features, other parity)
  a0 += __shfl_xor(a0, 32, 64);
  a1 += __shfl_xor(a1, 32, 64);
  float dv = dinv[gw];
  float2 hf = ((const float2*)hinf)[(size_t)gw * 32 + c];
  float2 h0f = ((const float2*)h0)[(size_t)gw * 32 + c];
  float o0 = 0.9f * (a0 + dv * dv * hf.x) + 0.1f * h0f.x;
  float o1 = 0.9f * (a1 + dv * dv * hf.y) + 0.1f * h0f.y;
  if (half == 0) {
    float2 ov; ov.x = o0; ov.y = o1;
    ((float2*)houtf)[(size_t)gw * 32 + c] = ov;
  } else if (WRITE_BF) {
    unsigned int pk = (unsigned int)f2bf(o0) | ((unsigned int)f2bf(o1) << 16);
    ((unsigned int*)houtb)[(size_t)gw * 32 + c] = pk;
  }
}

extern "C" void kernel_launch(void* const* d_in, const int* in_sizes, int n_in,
                              void* d_out, int out_size, void* d_ws, size_t ws_size,
                              hipStream_t stream) {
  const float* X  = (const float*)d_in[0];  // [N,512] f32
  const int*   EI = (const int*)d_in[1];    // [2,E] int32
  const float* W1 = (const float*)d_in[2];  // [512,256] f32
  const float* b1 = (const float*)d_in[3];  // [256] f32
  const float* W2 = (const float*)d_in[4];  // [256,64] f32
  const float* b2 = (const float*)d_in[5];  // [64] f32
  float* out = (float*)d_out;               // [N,64] f32

  const int N = in_sizes[0] / IN;  // 100000
  const int E = in_sizes[1] / 2;   // 3200000

  char* ws = (char*)d_ws;
  size_t o = 0;
  auto alloc = [&](size_t b) {
    char* p = ws + o;
    o = (o + b + 255) & ~(size_t)255;
    return p;
  };
  float*  H0f  = (float*)alloc((size_t)N * OUT * 4);
  ushort* H0b  = (ushort*)alloc((size_t)N * OUT * 2);
  float*  hAf  = (float*)alloc((size_t)N * OUT * 4);
  ushort* hAb  = (ushort*)alloc((size_t)N * OUT * 2);
  float*  hBf  = (float*)alloc((size_t)N * OUT * 4);
  ushort* hBb  = (ushort*)alloc((size_t)N * OUT * 2);
  ushort* h1   = (ushort*)alloc((size_t)N * HID * 2);
  ushort* W1T  = (ushort*)alloc((size_t)IN * HID * 2);
  ushort* W2T  = (ushort*)alloc((size_t)HID * OUT * 2);
  int*    cnt  = (int*)alloc((size_t)N * 4);
  int*    offs = (int*)alloc((size_t)(N + 1) * 4);
  int*    curs = (int*)alloc((size_t)N * 4);
  float*  dinv = (float*)alloc((size_t)N * 4);
  unsigned int* csr = (unsigned int*)alloc((size_t)E * 4);
  (void)ws_size; (void)n_in; (void)out_size;

  transpose_f32_bf16<<<(IN * HID + 255) / 256, 256, 0, stream>>>(W1, W1T, IN, HID);
  transpose_f32_bf16<<<(HID * OUT + 255) / 256, 256, 0, stream>>>(W2, W2T, HID, OUT);

  gemm1<<<dim3((N + 127) / 128, HID / 128), 256, 0, stream>>>(X, W1T, b1, h1, N);
  gemm2<<<(N + 127) / 128, 256, 0, stream>>>(h1, W2T, b2, H0f, H0b, N);

  hipMemsetAsync(cnt, 0, (size_t)N * 4, stream);
  count_deg<<<(E + 255) / 256, 256, 0, stream>>>(EI, cnt, E);
  calc_dinv<<<(N + 255) / 256, 256, 0, stream>>>(cnt, dinv, N);
  scan_kernel<<<1, 1024, 0, stream>>>(cnt, offs, curs, N);
  const int NCH = (E + CSR_CH - 1) / CSR_CH;
  fill_csr<<<NCH * 8, 256, 0, stream>>>(EI, curs, dinv, csr, E, N);

  const int pgrid = (N * OUT + 255) / 256;  // one wave per node
  prop_step<true><<<pgrid, 256, 0, stream>>>(H0f, H0b, hAf, hAb, H0f, offs, csr, dinv, N);
  for (int i = 0; i < 4; ++i) {
    prop_step<true><<<pgrid, 256, 0, stream>>>(hAf, hAb, hBf, hBb, H0f, offs, csr, dinv, N);
    prop_step<true><<<pgrid, 256, 0, stream>>>(hBf, hBb, hAf, hAb, H0f, offs, csr, dinv, N);
  }
  prop_step<false><<<pgrid, 256, 0, stream>>>(hAf, hAb, out, nullptr, H0f, offs, csr, dinv, N);
}

// Round 5
// 1370.029 us; speedup vs baseline: 1.0316x; 1.0276x over previous
//
#include <hip/hip_runtime.h>
#include <hip/hip_bf16.h>
#include <hip/hip_fp16.h>

// APPNP: h = MLP(x); 10x { h = 0.9 * (D^-1/2 (A+I) D^-1/2) h + 0.1 * h0 }
// fp32 in/out; GEMMs run bf16 MFMA with inline fp32->bf16 conversion.
// R4: byte-diet on the line-amplified paths (bf16 mirror of h, 4B/edge CSR).
// R5/R8 (bucket CSR, dst-range CSR) REVERTED: few-cursor atomics serialize;
//   block->XCD mapping is NOT bid%8 (R8: write amp unchanged) -> direct
//   scatter fill_csr (165us) is the proven best; its 197MB partial-line
//   drain is structural without writer placement control.
// R6: prop_step 2-edges-per-load (lanes 0-31 edge j, 32-63 edge j+1): neutral.
// R7 (GEMM reg-prefetch) REVERTED: prefetch regs live across barriers -> VGPR
//   100, occupancy 19%, WRITE 78->207MB (spill), 175us.
// R9: gemm1 staging via __builtin_amdgcn_global_load_lds (width 16) — the
//   compiler never auto-emits it (guide CM#1; +67% isolated, m193). A tile
//   stays fp32 in LDS (cvt moved to frag read; zero staging VALU), 16B-chunk
//   XOR swizzle c^=(row&7); B tile bf16, c^=(row^row>>2)&3. Swizzle applied
//   on the GLOBAL source + same XOR on LDS read; LDS dest linear (rule #21).

typedef __bf16 bf16x8 __attribute__((ext_vector_type(8)));
typedef float f32x4 __attribute__((ext_vector_type(4)));

static constexpr int IN = 512, HID = 256, OUT = 64;
static constexpr int LDT = 40;   // LDS row stride (bf16 elems) for gemm2

static __device__ __forceinline__ ushort f2bf(float f) {
  __hip_bfloat16 b = __float2bfloat16(f);
  return *reinterpret_cast<ushort*>(&b);
}
static __device__ __forceinline__ float bf2f(ushort u) {
  unsigned int x = ((unsigned int)u) << 16;
  return __uint_as_float(x);
}
// decode low-15-bit fp16 (sign=0) weight
static __device__ __forceinline__ float h15f(unsigned int u) {
  ushort hb = (ushort)(u & 0x7FFFu);
  __half h = *reinterpret_cast<__half*>(&hb);
  return __half2float(h);
}

static __device__ __forceinline__ void gload16(const void* g, void* l) {
  __builtin_amdgcn_global_load_lds(
      (const __attribute__((address_space(1))) void*)g,
      (__attribute__((address_space(3))) void*)l, 16, 0, 0);
}

// ---------------- transpose fp32 [K][C] -> bf16 [C][K] ----------------
__global__ void transpose_f32_bf16(const float* __restrict__ in, ushort* __restrict__ out,
                                   int K, int C) {
  int idx = blockIdx.x * 256 + threadIdx.x;
  if (idx < K * C) {
    int n = idx / K, k = idx % K;
    out[idx] = f2bf(in[k * C + n]);
  }
}

// ---------------- GEMM1: h1 = relu(X @ W1 + b1) ----------------
// X [M,512] fp32, W1T [256,512] bf16, h1 [M,256] bf16. Tile 128x128x32.
// Staging: global_load_lds direct; A kept fp32 in LDS (cvt at frag read).
__global__ __launch_bounds__(256) void gemm1(const float* __restrict__ X,
                                             const ushort* __restrict__ W1T,
                                             const float* __restrict__ b1,
                                             ushort* __restrict__ h1, int M) {
  __shared__ __align__(16) float As[128 * 32];   // 16KB: X tile fp32, chunk-swizzled
  __shared__ __align__(16) ushort Bs[128 * 32];  // 8KB: W1T tile bf16, chunk-swizzled
  const int tid = threadIdx.x;
  const int m0 = blockIdx.x * 128;
  const int n0 = blockIdx.y * 128;
  const int lane = tid & 63, w = tid >> 6;
  const int wr = w >> 1, wc = w & 1;
  const int lm = lane & 15, lq = lane >> 4;
  const int wbase = w * 64;  // wave-uniform slot within a 256-lane issue

  f32x4 acc[4][4] = {};

  for (int k0 = 0; k0 < IN; k0 += 32) {
    // A: 128 rows x 8 chunks of 16B (4 floats). 4 issues x 256 lanes.
    // LDS dest linear in idx; source chunk pre-swizzled: sch = ch ^ (row&7).
#pragma unroll
    for (int i = 0; i < 4; ++i) {
      int idx = i * 256 + tid;
      int row = idx >> 3, ch = idx & 7;
      int gm = m0 + row; gm = gm < M ? gm : M - 1;
      int sch = ch ^ (row & 7);
      gload16(&X[(size_t)gm * IN + k0 + sch * 4], &As[(i * 256 + wbase) * 4]);
    }
    // B: 128 rows x 4 chunks of 16B (8 bf16). 2 issues x 256 lanes.
    // key = (row ^ row>>2)&3 spreads frag-read banks 8-wide.
#pragma unroll
    for (int i = 0; i < 2; ++i) {
      int idx = i * 256 + tid;
      int row = idx >> 2, ch = idx & 3;
      int sch = ch ^ ((row ^ (row >> 2)) & 3);
      gload16(&W1T[(size_t)(n0 + row) * IN + k0 + sch * 8], &Bs[(i * 256 + wbase) * 8]);
    }
    __syncthreads();

    bf16x8 af[4], bq[4];
#pragma unroll
    for (int mi = 0; mi < 4; ++mi) {
      int r = wr * 64 + mi * 16 + lm;
      int k7 = r & 7;
      float4 x0 = *reinterpret_cast<const float4*>(&As[r * 32 + ((2 * lq) ^ k7) * 4]);
      float4 x1 = *reinterpret_cast<const float4*>(&As[r * 32 + ((2 * lq + 1) ^ k7) * 4]);
      union { ushort u[8]; bf16x8 v; } cv;
      cv.u[0] = f2bf(x0.x); cv.u[1] = f2bf(x0.y); cv.u[2] = f2bf(x0.z); cv.u[3] = f2bf(x0.w);
      cv.u[4] = f2bf(x1.x); cv.u[5] = f2bf(x1.y); cv.u[6] = f2bf(x1.z); cv.u[7] = f2bf(x1.w);
      af[mi] = cv.v;
    }
#pragma unroll
    for (int ni = 0; ni < 4; ++ni) {
      int r = wc * 64 + ni * 16 + lm;
      int key = (r ^ (r >> 2)) & 3;
      bq[ni] = *reinterpret_cast<const bf16x8*>(&Bs[r * 32 + (lq ^ key) * 8]);
    }
#pragma unroll
    for (int mi = 0; mi < 4; ++mi)
#pragma unroll
      for (int ni = 0; ni < 4; ++ni)
        acc[mi][ni] = __builtin_amdgcn_mfma_f32_16x16x32_bf16(af[mi], bq[ni], acc[mi][ni], 0, 0, 0);
    __syncthreads();
  }

#pragma unroll
  for (int ni = 0; ni < 4; ++ni) {
    int col = n0 + wc * 64 + ni * 16 + lm;
    float bias = b1[col];
#pragma unroll
    for (int mi = 0; mi < 4; ++mi) {
#pragma unroll
      for (int rg = 0; rg < 4; ++rg) {
        int row = m0 + wr * 64 + mi * 16 + lq * 4 + rg;
        if (row < M) {
          float v = acc[mi][ni][rg] + bias;
          v = v > 0.f ? v : 0.f;
          h1[(size_t)row * HID + col] = f2bf(v);
        }
      }
    }
  }
}

// ---------------- GEMM2: H0 = h1 @ W2 + b2, fp32 + bf16 mirror out ----------------
__global__ __launch_bounds__(256) void gemm2(const ushort* __restrict__ h1,
                                             const ushort* __restrict__ W2T,
                                             const float* __restrict__ b2,
                                             float* __restrict__ H0f,
                                             ushort* __restrict__ H0b, int M) {
  __shared__ __align__(16) ushort As[128 * LDT];
  __shared__ __align__(16) ushort Bs[64 * LDT];
  const int tid = threadIdx.x;
  const int m0 = blockIdx.x * 128;
  const int lane = tid & 63, w = tid >> 6;
  const int lm = lane & 15, lq = lane >> 4;
  const int c = tid & 3, r = tid >> 2;

  f32x4 acc[2][4] = {};

  for (int k0 = 0; k0 < HID; k0 += 32) {
#pragma unroll
    for (int rr = 0; rr < 2; ++rr) {
      int m = r + rr * 64;
      int gm = m0 + m; gm = gm < M ? gm : M - 1;
      *reinterpret_cast<int4*>(&As[m * LDT + c * 8]) =
          *reinterpret_cast<const int4*>(&h1[(size_t)gm * HID + k0 + c * 8]);
    }
    *reinterpret_cast<int4*>(&Bs[r * LDT + c * 8]) =
        *reinterpret_cast<const int4*>(&W2T[(size_t)r * HID + k0 + c * 8]);
    __syncthreads();
    bf16x8 af[2], bq[4];
#pragma unroll
    for (int mi = 0; mi < 2; ++mi)
      af[mi] = *reinterpret_cast<const bf16x8*>(&As[(w * 32 + mi * 16 + lm) * LDT + lq * 8]);
#pragma unroll
    for (int ni = 0; ni < 4; ++ni)
      bq[ni] = *reinterpret_cast<const bf16x8*>(&Bs[(ni * 16 + lm) * LDT + lq * 8]);
#pragma unroll
    for (int mi = 0; mi < 2; ++mi)
#pragma unroll
      for (int ni = 0; ni < 4; ++ni)
        acc[mi][ni] = __builtin_amdgcn_mfma_f32_16x16x32_bf16(af[mi], bq[ni], acc[mi][ni], 0, 0, 0);
    __syncthreads();
  }

#pragma unroll
  for (int ni = 0; ni < 4; ++ni) {
    int col = ni * 16 + lm;
    float bias = b2[col];
#pragma unroll
    for (int mi = 0; mi < 2; ++mi) {
#pragma unroll
      for (int rg = 0; rg < 4; ++rg) {
        int row = m0 + w * 32 + mi * 16 + lq * 4 + rg;
        if (row < M) {
          float v = acc[mi][ni][rg] + bias;
          H0f[(size_t)row * OUT + col] = v;
          H0b[(size_t)row * OUT + col] = f2bf(v);
        }
      }
    }
  }
}

// ---------------- degree / dinv / scan / CSR ----------------
__global__ void count_deg(const int* __restrict__ ei, int* __restrict__ cnt, int E) {
  int e = blockIdx.x * 256 + threadIdx.x;
  if (e < E) atomicAdd(&cnt[ei[E + e]], 1);
}

__global__ void calc_dinv(const int* __restrict__ cnt, float* __restrict__ dinv, int n) {
  int v = blockIdx.x * 256 + threadIdx.x;
  if (v < n) dinv[v] = rsqrtf((float)cnt[v] + 1.0f);  // +1: self-loop
}

// single-block exclusive scan of cnt[n] -> offs[n+1], cursor[n]; 4 elems/thread/iter
__global__ __launch_bounds__(1024) void scan_kernel(const int* __restrict__ cnt,
                                                    int* __restrict__ offs,
                                                    int* __restrict__ cursor, int n) {
  __shared__ int wsum[16];
  __shared__ int woff[16];
  __shared__ int carry_s;
  const int tid = threadIdx.x;
  const int lane = tid & 63, wid = tid >> 6;
  if (tid == 0) carry_s = 0;
  __syncthreads();
  for (int base = 0; base < n; base += 4096) {
    int i0 = base + tid * 4;
    int x[4];
#pragma unroll
    for (int j = 0; j < 4; ++j) x[j] = (i0 + j < n) ? cnt[i0 + j] : 0;
    int tsum = x[0] + x[1] + x[2] + x[3];
    int val = tsum;
#pragma unroll
    for (int d = 1; d < 64; d <<= 1) {
      int t = __shfl_up(val, d, 64);
      if (lane >= d) val += t;
    }
    if (lane == 63) wsum[wid] = val;
    __syncthreads();
    if (wid == 0) {
      int s = (lane < 16) ? wsum[lane] : 0;
      int sv = s;
#pragma unroll
      for (int d = 1; d < 16; d <<= 1) {
        int t = __shfl_up(sv, d, 64);
        if (lane >= d) sv += t;
      }
      if (lane < 16) woff[lane] = sv - s;
    }
    __syncthreads();
    int excl = carry_s + woff[wid] + (val - tsum);
#pragma unroll
    for (int j = 0; j < 4; ++j) {
      if (i0 + j < n) { offs[i0 + j] = excl; cursor[i0 + j] = excl; }
      excl += x[j];
    }
    __syncthreads();
    if (tid == 1023) carry_s = excl;
    __syncthreads();
  }
  if (tid == 0) offs[n] = carry_s;
}

// pack (src<<15) | fp16bits(w): src < 2^17, w > 0 so fp16 sign bit is dropped
__global__ void fill_csr(const int* __restrict__ ei, int* __restrict__ cursor,
                         const float* __restrict__ dinv, unsigned int* __restrict__ csr,
                         int E) {
  int e = blockIdx.x * 256 + threadIdx.x;
  if (e < E) {
    int s = ei[e], d = ei[E + e];
    int p = atomicAdd(&cursor[d], 1);
    float w = dinv[s] * dinv[d];
    __half hw = __float2half(w);
    unsigned int hb = *reinterpret_cast<ushort*>(&hw);
    csr[p] = (((unsigned int)s) << 15) | hb;
  }
}

// ---------------- propagation: one wave per node ----------------
// Lane l batch-fetches csr[base+l] (256B coalesced per 64 edges), shfl-broadcasts.
// 2 edges per load: lanes 0-31 read edge (j+2k) row as uint (features 2c,2c+1),
// lanes 32-63 read edge (j+2k+1). 16 loads in flight = 32 edges. Even/odd-edge
// partial sums combined with shfl_xor(32); fp32 write by lanes<32, bf16 by lanes>=32.
template <bool WRITE_BF>
__global__ __launch_bounds__(256) void prop_step(const float* __restrict__ hinf,
                                                 const ushort* __restrict__ hinb,
                                                 float* __restrict__ houtf,
                                                 ushort* __restrict__ houtb,
                                                 const float* __restrict__ h0,
                                                 const int* __restrict__ offs,
                                                 const unsigned int* __restrict__ csr,
                                                 const float* __restrict__ dinv, int n) {
  int gw = (blockIdx.x * 256 + threadIdx.x) >> 6;
  int lane = threadIdx.x & 63;
  if (gw >= n) return;
  const unsigned int* hin32 = (const unsigned int*)hinb;
  const int c = lane & 31;       // feature pair index (features 2c, 2c+1)
  const int half = lane >> 5;    // 0: even-slot edges, 1: odd-slot edges
  float alo[8], ahi[8];
#pragma unroll
  for (int k = 0; k < 8; ++k) { alo[k] = 0.f; ahi[k] = 0.f; }
  int e0 = offs[gw], e1 = offs[gw + 1];
  for (int base = e0; base < e1; base += 64) {
    int rem = e1 - base;
    // padded lanes: u=0 -> src=0, w=+0 (row 0 is valid; contribution is 0)
    unsigned int my = (lane < rem) ? csr[base + lane] : 0u;
    int cnt = rem < 64 ? rem : 64;
    int cnt32 = (cnt + 31) & ~31;
    for (int j = 0; j < cnt32; j += 32) {
      unsigned int u[16];
#pragma unroll
      for (int k = 0; k < 16; ++k)
        u[k] = (unsigned int)__shfl((int)my, j + 2 * k + half);
      unsigned int v[16];
#pragma unroll
      for (int k = 0; k < 16; ++k)
        v[k] = hin32[(size_t)(u[k] >> 15) * 32 + c];
#pragma unroll
      for (int k = 0; k < 16; ++k) {
        float w = h15f(u[k]);
        float f0 = __uint_as_float(v[k] << 16);
        float f1 = __uint_as_float(v[k] & 0xFFFF0000u);
        alo[k & 7] = fmaf(w, f0, alo[k & 7]);
        ahi[k & 7] = fmaf(w, f1, ahi[k & 7]);
      }
    }
  }
  float a0 = ((alo[0] + alo[1]) + (alo[2] + alo[3])) + ((alo[4] + alo[5]) + (alo[6] + alo[7]));
  float a1 = ((ahi[0] + ahi[1]) + (ahi[2] + ahi[3])) + ((ahi[4] + ahi[5]) + (ahi[6] + ahi[7]));
  // combine even/odd-edge halves (partner lane holds same features, other parity)
  a0 += __shfl_xor(a0, 32, 64);
  a1 += __shfl_xor(a1, 32, 64);
  float dv = dinv[gw];
  float2 hf = ((const float2*)hinf)[(size_t)gw * 32 + c];
  float2 h0f = ((const float2*)h0)[(size_t)gw * 32 + c];
  float o0 = 0.9f * (a0 + dv * dv * hf.x) + 0.1f * h0f.x;
  float o1 = 0.9f * (a1 + dv * dv * hf.y) + 0.1f * h0f.y;
  if (half == 0) {
    float2 ov; ov.x = o0; ov.y = o1;
    ((float2*)houtf)[(size_t)gw * 32 + c] = ov;
  } else if (WRITE_BF) {
    unsigned int pk = (unsigned int)f2bf(o0) | ((unsigned int)f2bf(o1) << 16);
    ((unsigned int*)houtb)[(size_t)gw * 32 + c] = pk;
  }
}

extern "C" void kernel_launch(void* const* d_in, const int* in_sizes, int n_in,
                              void* d_out, int out_size, void* d_ws, size_t ws_size,
                              hipStream_t stream) {
  const float* X  = (const float*)d_in[0];  // [N,512] f32
  const int*   EI = (const int*)d_in[1];    // [2,E] int32
  const float* W1 = (const float*)d_in[2];  // [512,256] f32
  const float* b1 = (const float*)d_in[3];  // [256] f32
  const float* W2 = (const float*)d_in[4];  // [256,64] f32
  const float* b2 = (const float*)d_in[5];  // [64] f32
  float* out = (float*)d_out;               // [N,64] f32

  const int N = in_sizes[0] / IN;  // 100000
  const int E = in_sizes[1] / 2;   // 3200000

  char* ws = (char*)d_ws;
  size_t o = 0;
  auto alloc = [&](size_t b) {
    char* p = ws + o;
    o = (o + b + 255) & ~(size_t)255;
    return p;
  };
  float*  H0f  = (float*)alloc((size_t)N * OUT * 4);
  ushort* H0b  = (ushort*)alloc((size_t)N * OUT * 2);
  float*  hAf  = (float*)alloc((size_t)N * OUT * 4);
  ushort* hAb  = (ushort*)alloc((size_t)N * OUT * 2);
  float*  hBf  = (float*)alloc((size_t)N * OUT * 4);
  ushort* hBb  = (ushort*)alloc((size_t)N * OUT * 2);
  ushort* h1   = (ushort*)alloc((size_t)N * HID * 2);
  ushort* W1T  = (ushort*)alloc((size_t)IN * HID * 2);
  ushort* W2T  = (ushort*)alloc((size_t)HID * OUT * 2);
  int*    cnt  = (int*)alloc((size_t)N * 4);
  int*    offs = (int*)alloc((size_t)(N + 1) * 4);
  int*    curs = (int*)alloc((size_t)N * 4);
  float*  dinv = (float*)alloc((size_t)N * 4);
  unsigned int* csr = (unsigned int*)alloc((size_t)E * 4);
  (void)ws_size; (void)n_in; (void)out_size;

  transpose_f32_bf16<<<(IN * HID + 255) / 256, 256, 0, stream>>>(W1, W1T, IN, HID);
  transpose_f32_bf16<<<(HID * OUT + 255) / 256, 256, 0, stream>>>(W2, W2T, HID, OUT);

  gemm1<<<dim3((N + 127) / 128, HID / 128), 256, 0, stream>>>(X, W1T, b1, h1, N);
  gemm2<<<(N + 127) / 128, 256, 0, stream>>>(h1, W2T, b2, H0f, H0b, N);

  hipMemsetAsync(cnt, 0, (size_t)N * 4, stream);
  count_deg<<<(E + 255) / 256, 256, 0, stream>>>(EI, cnt, E);
  calc_dinv<<<(N + 255) / 256, 256, 0, stream>>>(cnt, dinv, N);
  scan_kernel<<<1, 1024, 0, stream>>>(cnt, offs, curs, N);
  fill_csr<<<(E + 255) / 256, 256, 0, stream>>>(EI, curs, dinv, csr, E);

  const int pgrid = (N * OUT + 255) / 256;  // one wave per node
  prop_step<true><<<pgrid, 256, 0, stream>>>(H0f, H0b, hAf, hAb, H0f, offs, csr, dinv, N);
  for (int i = 0; i < 4; ++i) {
    prop_step<true><<<pgrid, 256, 0, stream>>>(hAf, hAb, hBf, hBb, H0f, offs, csr, dinv, N);
    prop_step<true><<<pgrid, 256, 0, stream>>>(hBf, hBb, hAf, hAb, H0f, offs, csr, dinv, N);
  }
  prop_step<false><<<pgrid, 256, 0, stream>>>(hAf, hAb, out, nullptr, H0f, offs, csr, dinv, N);
}

// Round 6
// 1349.249 us; speedup vs baseline: 1.0475x; 1.0154x over previous
//
#include <hip/hip_runtime.h>
#include <hip/hip_bf16.h>
#include <hip/hip_fp16.h>

// APPNP: h = MLP(x); 10x { h = 0.9 * (D^-1/2 (A+I) D^-1/2) h + 0.1 * h0 }
// fp32 in/out; GEMMs run bf16 MFMA with inline fp32->bf16 conversion.
// R4: byte-diet on the line-amplified paths (bf16 mirror of h, 4B/edge CSR).
// R5/R8 (bucket CSR, dst-range CSR) REVERTED: few-cursor atomics serialize;
//   block->XCD mapping is NOT bid%8 -> direct scatter fill_csr (165us) wins.
// R6: prop_step 2-edges-per-load: neutral.
// R7 (GEMM reg-prefetch) REVERTED: prefetch regs live across barriers ->
//   VGPR 100, occupancy 19%, WRITE 78->207MB (spill), 175us.
// R9: gemm1 staging via global_load_lds (width 16): VALUBusy 14->9.5% but
//   155us unchanged -> staging VALU was not the binder.
// R10: gemm1 2-phase double-buffer (catalog T3-minimum / m230 pattern):
//   STAGE(buf^1, k+1) -> compute buf -> vmcnt(0)+barrier. Load latency now
//   hides under the compute phase; ONE barrier per k-step. LDS 24->48KB
//   (3 blocks/CU). Grid swapped to dim3(2, mblocks) so the two col-blocks
//   of an X panel are dispatch-adjacent (X L2/L3 temporal locality).

typedef __bf16 bf16x8 __attribute__((ext_vector_type(8)));
typedef float f32x4 __attribute__((ext_vector_type(4)));

static constexpr int IN = 512, HID = 256, OUT = 64;
static constexpr int LDT = 40;   // LDS row stride (bf16 elems) for gemm2

static __device__ __forceinline__ ushort f2bf(float f) {
  __hip_bfloat16 b = __float2bfloat16(f);
  return *reinterpret_cast<ushort*>(&b);
}
static __device__ __forceinline__ float bf2f(ushort u) {
  unsigned int x = ((unsigned int)u) << 16;
  return __uint_as_float(x);
}
// decode low-15-bit fp16 (sign=0) weight
static __device__ __forceinline__ float h15f(unsigned int u) {
  ushort hb = (ushort)(u & 0x7FFFu);
  __half h = *reinterpret_cast<__half*>(&hb);
  return __half2float(h);
}

static __device__ __forceinline__ void gload16(const void* g, void* l) {
  __builtin_amdgcn_global_load_lds(
      (const __attribute__((address_space(1))) void*)g,
      (__attribute__((address_space(3))) void*)l, 16, 0, 0);
}

// ---------------- transpose fp32 [K][C] -> bf16 [C][K] ----------------
__global__ void transpose_f32_bf16(const float* __restrict__ in, ushort* __restrict__ out,
                                   int K, int C) {
  int idx = blockIdx.x * 256 + threadIdx.x;
  if (idx < K * C) {
    int n = idx / K, k = idx % K;
    out[idx] = f2bf(in[k * C + n]);
  }
}

// ---------------- GEMM1: h1 = relu(X @ W1 + b1) ----------------
// X [M,512] fp32, W1T [256,512] bf16, h1 [M,256] bf16. Tile 128x128x32.
// Staging: global_load_lds direct into double-buffered LDS; A kept fp32 in
// LDS (cvt at frag read). 2-phase: stage k+1 before computing k.
__global__ __launch_bounds__(256) void gemm1(const float* __restrict__ X,
                                             const ushort* __restrict__ W1T,
                                             const float* __restrict__ b1,
                                             ushort* __restrict__ h1, int M) {
  __shared__ __align__(16) float As[2][128 * 32];   // 2x16KB fp32, chunk-swizzled
  __shared__ __align__(16) ushort Bs[2][128 * 32];  // 2x8KB bf16, chunk-swizzled
  const int tid = threadIdx.x;
  const int m0 = blockIdx.y * 128;
  const int n0 = blockIdx.x * 128;
  const int lane = tid & 63, w = tid >> 6;
  const int wr = w >> 1, wc = w & 1;
  const int lm = lane & 15, lq = lane >> 4;
  const int wbase = w * 64;  // wave-uniform slot within a 256-lane issue

  // staging address components (loop-invariant)
  auto STAGE = [&](int k0, int buf) {
    // A: 128 rows x 8 chunks of 16B (4 floats). 4 issues x 256 lanes.
    // LDS dest linear in idx; source chunk pre-swizzled: sch = ch ^ (row&7).
#pragma unroll
    for (int i = 0; i < 4; ++i) {
      int idx = i * 256 + tid;
      int row = idx >> 3, ch = idx & 7;
      int gm = m0 + row; gm = gm < M ? gm : M - 1;
      int sch = ch ^ (row & 7);
      gload16(&X[(size_t)gm * IN + k0 + sch * 4], &As[buf][(i * 256 + wbase) * 4]);
    }
    // B: 128 rows x 4 chunks of 16B (8 bf16). 2 issues x 256 lanes.
#pragma unroll
    for (int i = 0; i < 2; ++i) {
      int idx = i * 256 + tid;
      int row = idx >> 2, ch = idx & 3;
      int sch = ch ^ ((row ^ (row >> 2)) & 3);
      gload16(&W1T[(size_t)(n0 + row) * IN + k0 + sch * 8], &Bs[buf][(i * 256 + wbase) * 8]);
    }
  };

  f32x4 acc[4][4] = {};

  STAGE(0, 0);
  __syncthreads();  // drains prologue loads

  int cur = 0;
  for (int k0 = 0; k0 < IN; k0 += 32) {
    if (k0 + 32 < IN) STAGE(k0 + 32, cur ^ 1);  // in flight under compute

    bf16x8 af[4], bq[4];
#pragma unroll
    for (int mi = 0; mi < 4; ++mi) {
      int r = wr * 64 + mi * 16 + lm;
      int k7 = r & 7;
      float4 x0 = *reinterpret_cast<const float4*>(&As[cur][r * 32 + ((2 * lq) ^ k7) * 4]);
      float4 x1 = *reinterpret_cast<const float4*>(&As[cur][r * 32 + ((2 * lq + 1) ^ k7) * 4]);
      union { ushort u[8]; bf16x8 v; } cv;
      cv.u[0] = f2bf(x0.x); cv.u[1] = f2bf(x0.y); cv.u[2] = f2bf(x0.z); cv.u[3] = f2bf(x0.w);
      cv.u[4] = f2bf(x1.x); cv.u[5] = f2bf(x1.y); cv.u[6] = f2bf(x1.z); cv.u[7] = f2bf(x1.w);
      af[mi] = cv.v;
    }
#pragma unroll
    for (int ni = 0; ni < 4; ++ni) {
      int r = wc * 64 + ni * 16 + lm;
      int key = (r ^ (r >> 2)) & 3;
      bq[ni] = *reinterpret_cast<const bf16x8*>(&Bs[cur][r * 32 + (lq ^ key) * 8]);
    }
#pragma unroll
    for (int mi = 0; mi < 4; ++mi)
#pragma unroll
      for (int ni = 0; ni < 4; ++ni)
        acc[mi][ni] = __builtin_amdgcn_mfma_f32_16x16x32_bf16(af[mi], bq[ni], acc[mi][ni], 0, 0, 0);

    __syncthreads();  // drains staged loads (landed under compute) + LDS reads
    cur ^= 1;
  }

#pragma unroll
  for (int ni = 0; ni < 4; ++ni) {
    int col = n0 + wc * 64 + ni * 16 + lm;
    float bias = b1[col];
#pragma unroll
    for (int mi = 0; mi < 4; ++mi) {
#pragma unroll
      for (int rg = 0; rg < 4; ++rg) {
        int row = m0 + wr * 64 + mi * 16 + lq * 4 + rg;
        if (row < M) {
          float v = acc[mi][ni][rg] + bias;
          v = v > 0.f ? v : 0.f;
          h1[(size_t)row * HID + col] = f2bf(v);
        }
      }
    }
  }
}

// ---------------- GEMM2: H0 = h1 @ W2 + b2, fp32 + bf16 mirror out ----------------
__global__ __launch_bounds__(256) void gemm2(const ushort* __restrict__ h1,
                                             const ushort* __restrict__ W2T,
                                             const float* __restrict__ b2,
                                             float* __restrict__ H0f,
                                             ushort* __restrict__ H0b, int M) {
  __shared__ __align__(16) ushort As[128 * LDT];
  __shared__ __align__(16) ushort Bs[64 * LDT];
  const int tid = threadIdx.x;
  const int m0 = blockIdx.x * 128;
  const int lane = tid & 63, w = tid >> 6;
  const int lm = lane & 15, lq = lane >> 4;
  const int c = tid & 3, r = tid >> 2;

  f32x4 acc[2][4] = {};

  for (int k0 = 0; k0 < HID; k0 += 32) {
#pragma unroll
    for (int rr = 0; rr < 2; ++rr) {
      int m = r + rr * 64;
      int gm = m0 + m; gm = gm < M ? gm : M - 1;
      *reinterpret_cast<int4*>(&As[m * LDT + c * 8]) =
          *reinterpret_cast<const int4*>(&h1[(size_t)gm * HID + k0 + c * 8]);
    }
    *reinterpret_cast<int4*>(&Bs[r * LDT + c * 8]) =
        *reinterpret_cast<const int4*>(&W2T[(size_t)r * HID + k0 + c * 8]);
    __syncthreads();
    bf16x8 af[2], bq[4];
#pragma unroll
    for (int mi = 0; mi < 2; ++mi)
      af[mi] = *reinterpret_cast<const bf16x8*>(&As[(w * 32 + mi * 16 + lm) * LDT + lq * 8]);
#pragma unroll
    for (int ni = 0; ni < 4; ++ni)
      bq[ni] = *reinterpret_cast<const bf16x8*>(&Bs[(ni * 16 + lm) * LDT + lq * 8]);
#pragma unroll
    for (int mi = 0; mi < 2; ++mi)
#pragma unroll
      for (int ni = 0; ni < 4; ++ni)
        acc[mi][ni] = __builtin_amdgcn_mfma_f32_16x16x32_bf16(af[mi], bq[ni], acc[mi][ni], 0, 0, 0);
    __syncthreads();
  }

#pragma unroll
  for (int ni = 0; ni < 4; ++ni) {
    int col = ni * 16 + lm;
    float bias = b2[col];
#pragma unroll
    for (int mi = 0; mi < 2; ++mi) {
#pragma unroll
      for (int rg = 0; rg < 4; ++rg) {
        int row = m0 + w * 32 + mi * 16 + lq * 4 + rg;
        if (row < M) {
          float v = acc[mi][ni][rg] + bias;
          H0f[(size_t)row * OUT + col] = v;
          H0b[(size_t)row * OUT + col] = f2bf(v);
        }
      }
    }
  }
}

// ---------------- degree / dinv / scan / CSR ----------------
__global__ void count_deg(const int* __restrict__ ei, int* __restrict__ cnt, int E) {
  int e = blockIdx.x * 256 + threadIdx.x;
  if (e < E) atomicAdd(&cnt[ei[E + e]], 1);
}

__global__ void calc_dinv(const int* __restrict__ cnt, float* __restrict__ dinv, int n) {
  int v = blockIdx.x * 256 + threadIdx.x;
  if (v < n) dinv[v] = rsqrtf((float)cnt[v] + 1.0f);  // +1: self-loop
}

// single-block exclusive scan of cnt[n] -> offs[n+1], cursor[n]; 4 elems/thread/iter
__global__ __launch_bounds__(1024) void scan_kernel(const int* __restrict__ cnt,
                                                    int* __restrict__ offs,
                                                    int* __restrict__ cursor, int n) {
  __shared__ int wsum[16];
  __shared__ int woff[16];
  __shared__ int carry_s;
  const int tid = threadIdx.x;
  const int lane = tid & 63, wid = tid >> 6;
  if (tid == 0) carry_s = 0;
  __syncthreads();
  for (int base = 0; base < n; base += 4096) {
    int i0 = base + tid * 4;
    int x[4];
#pragma unroll
    for (int j = 0; j < 4; ++j) x[j] = (i0 + j < n) ? cnt[i0 + j] : 0;
    int tsum = x[0] + x[1] + x[2] + x[3];
    int val = tsum;
#pragma unroll
    for (int d = 1; d < 64; d <<= 1) {
      int t = __shfl_up(val, d, 64);
      if (lane >= d) val += t;
    }
    if (lane == 63) wsum[wid] = val;
    __syncthreads();
    if (wid == 0) {
      int s = (lane < 16) ? wsum[lane] : 0;
      int sv = s;
#pragma unroll
      for (int d = 1; d < 16; d <<= 1) {
        int t = __shfl_up(sv, d, 64);
        if (lane >= d) sv += t;
      }
      if (lane < 16) woff[lane] = sv - s;
    }
    __syncthreads();
    int excl = carry_s + woff[wid] + (val - tsum);
#pragma unroll
    for (int j = 0; j < 4; ++j) {
      if (i0 + j < n) { offs[i0 + j] = excl; cursor[i0 + j] = excl; }
      excl += x[j];
    }
    __syncthreads();
    if (tid == 1023) carry_s = excl;
    __syncthreads();
  }
  if (tid == 0) offs[n] = carry_s;
}

// pack (src<<15) | fp16bits(w): src < 2^17, w > 0 so fp16 sign bit is dropped
__global__ void fill_csr(const int* __restrict__ ei, int* __restrict__ cursor,
                         const float* __restrict__ dinv, unsigned int* __restrict__ csr,
                         int E) {
  int e = blockIdx.x * 256 + threadIdx.x;
  if (e < E) {
    int s = ei[e], d = ei[E + e];
    int p = atomicAdd(&cursor[d], 1);
    float w = dinv[s] * dinv[d];
    __half hw = __float2half(w);
    unsigned int hb = *reinterpret_cast<ushort*>(&hw);
    csr[p] = (((unsigned int)s) << 15) | hb;
  }
}

// ---------------- propagation: one wave per node ----------------
// Lane l batch-fetches csr[base+l] (256B coalesced per 64 edges), shfl-broadcasts.
// 2 edges per load: lanes 0-31 read edge (j+2k) row as uint (features 2c,2c+1),
// lanes 32-63 read edge (j+2k+1). 16 loads in flight = 32 edges. Even/odd-edge
// partial sums combined with shfl_xor(32); fp32 write by lanes<32, bf16 by lanes>=32.
template <bool WRITE_BF>
__global__ __launch_bounds__(256) void prop_step(const float* __restrict__ hinf,
                                                 const ushort* __restrict__ hinb,
                                                 float* __restrict__ houtf,
                                                 ushort* __restrict__ houtb,
                                                 const float* __restrict__ h0,
                                                 const int* __restrict__ offs,
                                                 const unsigned int* __restrict__ csr,
                                                 const float* __restrict__ dinv, int n) {
  int gw = (blockIdx.x * 256 + threadIdx.x) >> 6;
  int lane = threadIdx.x & 63;
  if (gw >= n) return;
  const unsigned int* hin32 = (const unsigned int*)hinb;
  const int c = lane & 31;       // feature pair index (features 2c, 2c+1)
  const int half = lane >> 5;    // 0: even-slot edges, 1: odd-slot edges
  float alo[8], ahi[8];
#pragma unroll
  for (int k = 0; k < 8; ++k) { alo[k] = 0.f; ahi[k] = 0.f; }
  int e0 = offs[gw], e1 = offs[gw + 1];
  for (int base = e0; base < e1; base += 64) {
    int rem = e1 - base;
    // padded lanes: u=0 -> src=0, w=+0 (row 0 is valid; contribution is 0)
    unsigned int my = (lane < rem) ? csr[base + lane] : 0u;
    int cnt = rem < 64 ? rem : 64;
    int cnt32 = (cnt + 31) & ~31;
    for (int j = 0; j < cnt32; j += 32) {
      unsigned int u[16];
#pragma unroll
      for (int k = 0; k < 16; ++k)
        u[k] = (unsigned int)__shfl((int)my, j + 2 * k + half);
      unsigned int v[16];
#pragma unroll
      for (int k = 0; k < 16; ++k)
        v[k] = hin32[(size_t)(u[k] >> 15) * 32 + c];
#pragma unroll
      for (int k = 0; k < 16; ++k) {
        float w = h15f(u[k]);
        float f0 = __uint_as_float(v[k] << 16);
        float f1 = __uint_as_float(v[k] & 0xFFFF0000u);
        alo[k & 7] = fmaf(w, f0, alo[k & 7]);
        ahi[k & 7] = fmaf(w, f1, ahi[k & 7]);
      }
    }
  }
  float a0 = ((alo[0] + alo[1]) + (alo[2] + alo[3])) + ((alo[4] + alo[5]) + (alo[6] + alo[7]));
  float a1 = ((ahi[0] + ahi[1]) + (ahi[2] + ahi[3])) + ((ahi[4] + ahi[5]) + (ahi[6] + ahi[7]));
  // combine even/odd-edge halves (partner lane holds same features, other parity)
  a0 += __shfl_xor(a0, 32, 64);
  a1 += __shfl_xor(a1, 32, 64);
  float dv = dinv[gw];
  float2 hf = ((const float2*)hinf)[(size_t)gw * 32 + c];
  float2 h0f = ((const float2*)h0)[(size_t)gw * 32 + c];
  float o0 = 0.9f * (a0 + dv * dv * hf.x) + 0.1f * h0f.x;
  float o1 = 0.9f * (a1 + dv * dv * hf.y) + 0.1f * h0f.y;
  if (half == 0) {
    float2 ov; ov.x = o0; ov.y = o1;
    ((float2*)houtf)[(size_t)gw * 32 + c] = ov;
  } else if (WRITE_BF) {
    unsigned int pk = (unsigned int)f2bf(o0) | ((unsigned int)f2bf(o1) << 16);
    ((unsigned int*)houtb)[(size_t)gw * 32 + c] = pk;
  }
}

extern "C" void kernel_launch(void* const* d_in, const int* in_sizes, int n_in,
                              void* d_out, int out_size, void* d_ws, size_t ws_size,
                              hipStream_t stream) {
  const float* X  = (const float*)d_in[0];  // [N,512] f32
  const int*   EI = (const int*)d_in[1];    // [2,E] int32
  const float* W1 = (const float*)d_in[2];  // [512,256] f32
  const float* b1 = (const float*)d_in[3];  // [256] f32
  const float* W2 = (const float*)d_in[4];  // [256,64] f32
  const float* b2 = (const float*)d_in[5];  // [64] f32
  float* out = (float*)d_out;               // [N,64] f32

  const int N = in_sizes[0] / IN;  // 100000
  const int E = in_sizes[1] / 2;   // 3200000

  char* ws = (char*)d_ws;
  size_t o = 0;
  auto alloc = [&](size_t b) {
    char* p = ws + o;
    o = (o + b + 255) & ~(size_t)255;
    return p;
  };
  float*  H0f  = (float*)alloc((size_t)N * OUT * 4);
  ushort* H0b  = (ushort*)alloc((size_t)N * OUT * 2);
  float*  hAf  = (float*)alloc((size_t)N * OUT * 4);
  ushort* hAb  = (ushort*)alloc((size_t)N * OUT * 2);
  float*  hBf  = (float*)alloc((size_t)N * OUT * 4);
  ushort* hBb  = (ushort*)alloc((size_t)N * OUT * 2);
  ushort* h1   = (ushort*)alloc((size_t)N * HID * 2);
  ushort* W1T  = (ushort*)alloc((size_t)IN * HID * 2);
  ushort* W2T  = (ushort*)alloc((size_t)HID * OUT * 2);
  int*    cnt  = (int*)alloc((size_t)N * 4);
  int*    offs = (int*)alloc((size_t)(N + 1) * 4);
  int*    curs = (int*)alloc((size_t)N * 4);
  float*  dinv = (float*)alloc((size_t)N * 4);
  unsigned int* csr = (unsigned int*)alloc((size_t)E * 4);
  (void)ws_size; (void)n_in; (void)out_size;

  transpose_f32_bf16<<<(IN * HID + 255) / 256, 256, 0, stream>>>(W1, W1T, IN, HID);
  transpose_f32_bf16<<<(HID * OUT + 255) / 256, 256, 0, stream>>>(W2, W2T, HID, OUT);

  gemm1<<<dim3(HID / 128, (N + 127) / 128), 256, 0, stream>>>(X, W1T, b1, h1, N);
  gemm2<<<(N + 127) / 128, 256, 0, stream>>>(h1, W2T, b2, H0f, H0b, N);

  hipMemsetAsync(cnt, 0, (size_t)N * 4, stream);
  count_deg<<<(E + 255) / 256, 256, 0, stream>>>(EI, cnt, E);
  calc_dinv<<<(N + 255) / 256, 256, 0, stream>>>(cnt, dinv, N);
  scan_kernel<<<1, 1024, 0, stream>>>(cnt, offs, curs, N);
  fill_csr<<<(E + 255) / 256, 256, 0, stream>>>(EI, curs, dinv, csr, E);

  const int pgrid = (N * OUT + 255) / 256;  // one wave per node
  prop_step<true><<<pgrid, 256, 0, stream>>>(H0f, H0b, hAf, hAb, H0f, offs, csr, dinv, N);
  for (int i = 0; i < 4; ++i) {
    prop_step<true><<<pgrid, 256, 0, stream>>>(hAf, hAb, hBf, hBb, H0f, offs, csr, dinv, N);
    prop_step<true><<<pgrid, 256, 0, stream>>>(hBf, hBb, hAf, hAb, H0f, offs, csr, dinv, N);
  }
  prop_step<false><<<pgrid, 256, 0, stream>>>(hAf, hAb, out, nullptr, H0f, offs, csr, dinv, N);
}